// Round 1
// 386.863 us; speedup vs baseline: 1.0768x; 1.0768x over previous
//
#include <hip/hip_runtime.h>

// LSTMPricePredictor: B=4096, T=512, IN=1, H=50, 2 layers + FC(50->1)
// R17 = R16 + {x rank-1 via LDS stage, branch-peeled main loop, bias as
//   MFMA C-operand, unconditional h stores into dead k=50/51 slots,
//   2-rcp cell_update with c pre-scaled by 2*log2e}.
// Theory: R16 was issue/latency-bound (VALUBusy 50, Mfma 18, ~32% bubbles).
//   Wave-0's per-step global x load (32KB reuse = whole L1) + branchy body
//   + mask/mov overhead were the removable parts. Trans floor ~90 us stands.

typedef _Float16 half8 __attribute__((ext_vector_type(8)));
typedef float    f32x4 __attribute__((ext_vector_type(4)));

#define TT    512
#define HID   50
#define NB    16         // batch rows per block
#define XST   17         // xs row stride in floats (bank-conflict-free)
#define LOG2E 1.44269504f

// Weight A-fragment: lane's 8 fp16 for K-chunk `chunk`, pre-scaled by the
// gate's exp2 factor. Row m -> gate = m&3, cell = 4*wv + (m>>2).
// W is (200 x 50): element [gate*50+cell][k]. k>=50 rows are zero (the
// k=50/51 B-slots receive dead-lane junk and must multiply by zero).
__device__ __forceinline__ float4 make_wfrag(const float* W, int gate, int cell,
                                             int chunk, int quad, float scale) {
    half8 hv = {};
    #pragma unroll
    for (int j = 0; j < 8; ++j) {
        const int k = 32 * chunk + 8 * quad + j;
        float v = 0.0f;
        if (cell < HID && k < HID) v = W[(gate * HID + cell) * HID + k] * scale;
        hv[j] = (_Float16)v;
    }
    return __builtin_bit_cast(float4, hv);
}

// Shared-rcp LSTM cell update on pre-scaled gates, RAW hardware exp2.
//   a0 = -i*log2e, a1 = -f*log2e, a2 = 2g*log2e, a3 = -o*log2e.
// ct = c * 2*log2e is carried across steps (mul off the exp2 chain).
// Common denominator: c' = c*sig(f) + sig(i)*tanh(g)
//   = [ct*p + K(eg-1)*q] / (p*q) / K,  p=(1+ei)(1+eg), q=(1+ef), K=2log2e.
// Worst-case p*q <= 2^82 (gate |preact| <= ~14.2) -- no overflow.
__device__ __forceinline__ float cell_update(const f32x4 a, float& ct) {
    const float K  = 2.0f * LOG2E;
    const float ei = __builtin_amdgcn_exp2f(a[0]);   // e^{-i}
    const float ef = __builtin_amdgcn_exp2f(a[1]);   // e^{-f}
    const float eg = __builtin_amdgcn_exp2f(a[2]);   // e^{2g}
    const float eo = __builtin_amdgcn_exp2f(a[3]);   // e^{-o}
    const float p  = (1.0f + ei) * (1.0f + eg);
    const float q  = 1.0f + ef;
    const float t1 = __builtin_fmaf(eg, K, -K);                  // K*(eg-1)
    const float num = __builtin_fmaf(ct, p, t1 * q);
    ct = num * __builtin_amdgcn_rcpf(p * q);                     // K*c'
    const float ec = __builtin_amdgcn_exp2f(ct);                 // e^{2c'}
    return (ec - 1.0f) *
        __builtin_amdgcn_rcpf((1.0f + eo) * (ec + 1.0f));        // sig(o)*tanh(c')
}

#define PIN(f) asm volatile("" : "+v"(f.x), "+v"(f.y), "+v"(f.z), "+v"(f.w));
#define MFMA(af, b, c) __builtin_amdgcn_mfma_f32_16x16x32_f16(__builtin_bit_cast(half8, (af)), (b), (c), 0, 0, 0)

extern "C" __global__ __launch_bounds__(832, 4)
void lstm2_mfma_kernel(const float* __restrict__ x,
                       const float* __restrict__ W_ih0, const float* __restrict__ W_hh0,
                       const float* __restrict__ b_ih0, const float* __restrict__ b_hh0,
                       const float* __restrict__ W_ih1, const float* __restrict__ W_hh1,
                       const float* __restrict__ b_ih1, const float* __restrict__ b_hh1,
                       const float* __restrict__ fc_w, const float* __restrict__ fc_b,
                       float* __restrict__ out)
{
    // h-state in B-fragment layout: element (k, n) at (k>>5)*512 +
    // (((k&31)>>3)*16 + n)*8 + (k&7). k<50 = h; k=50/51 slots are dead
    // (zero A-weights) and absorb the cellD=50/51 junk stores.
    __shared__ _Float16 H0[2][1024];
    __shared__ _Float16 H1[2][1024];
    __shared__ float    xs[TT * XST];     // x staged fp32, [u*XST + col]
    __shared__ float    hfin[52 * NB];    // fp32 h1^(TT) for the FC epilogue

    const int tid  = threadIdx.x;
    const int lane = tid & 63;
    const int wv   = tid >> 6;            // wave 0..12 = gate-row tile
    const int b0   = blockIdx.x * NB;

    for (int i = tid; i < 1024; i += 832) {
        H0[0][i] = (_Float16)0.f; H0[1][i] = (_Float16)0.f;
        H1[0][i] = (_Float16)0.f; H1[1][i] = (_Float16)0.f;
    }
    // One-shot x stage: coalesced global read, stride-17 LDS write.
    for (int i = tid; i < NB * TT; i += 832) {
        const int row = i >> 9;           // batch row 0..15
        const int uu  = i & (TT - 1);     // timestep
        xs[uu * XST + row] = x[(size_t)(b0 + row) * TT + uu];
    }

    const int quad = lane >> 4;
    const int col  = lane & 15;           // batch column

    // ---- A-fragments (weights, exp2-prescaled), loaded once, pinned ----
    const int mrow  = lane & 15;          // A-row within tile
    const int gateA = mrow & 3;
    const int cellA = 4 * wv + (mrow >> 2);
    const float scA = (gateA == 2) ? 2.0f * LOG2E : -LOG2E;
    float4 A0c0 = make_wfrag(W_hh0, gateA, cellA, 0, quad, scA);
    float4 A0c1 = make_wfrag(W_hh0, gateA, cellA, 1, quad, scA);
    float4 Aic0 = make_wfrag(W_ih1, gateA, cellA, 0, quad, scA);
    float4 Aic1 = make_wfrag(W_ih1, gateA, cellA, 1, quad, scA);
    float4 Ahc0 = make_wfrag(W_hh1, gateA, cellA, 0, quad, scA);
    float4 Ahc1 = make_wfrag(W_hh1, gateA, cellA, 1, quad, scA);
    PIN(A0c0) PIN(A0c1) PIN(Aic0) PIN(Aic1) PIN(Ahc0) PIN(Ahc1)

    // ---- D-cell ownership: reg = gate, cell = 4*wv + quad, batch = col ----
    const int  cellD = 4 * wv + quad;
    const bool ewok  = (cellD < HID);
    f32x4 bias0, bias1, wx0;
    #pragma unroll
    for (int g = 0; g < 4; ++g) {
        const float s = (g == 2) ? 2.0f * LOG2E : -LOG2E;
        bias0[g] = ewok ? (b_ih0[g * HID + cellD] + b_hh0[g * HID + cellD]) * s : 0.f;
        bias1[g] = ewok ? (b_ih1[g * HID + cellD] + b_hh1[g * HID + cellD]) * s : 0.f;
        wx0[g]   = ewok ? W_ih0[g * HID + cellD] * s : 0.f;   // rank-1 x weights
    }
    // h write-back index in B-layout for (cellD, col); cellD=50/51 land in
    // the dead k=50/51 slots (zero A-weights) -> stores are unconditional.
    const int wi = (cellD >> 5) * 512 + (((cellD & 31) >> 3) * 16 + col) * 8 + (cellD & 7);

    float ct0 = 0.f, ct1 = 0.f;           // c * 2*log2e, both layers
    __syncthreads();

    // ---- prologue u=0: layer-0 only, h0^0 = 0 => gates = wx0*x_0 + bias0
    {
        const float xr = xs[col];
        f32x4 acc;
        #pragma unroll
        for (int g = 0; g < 4; ++g) acc[g] = __builtin_fmaf(wx0[g], xr, bias0[g]);
        const float h = cell_update(acc, ct0);
        H0[1][wi] = (_Float16)h;          // h0^1
        __syncthreads();
    }

    // ---- main loop u=1..TT-1: both layers, branch-free ----
    #pragma unroll 2
    for (int u = 1; u < TT; ++u) {
        const int pu = u & 1, pn = pu ^ 1;

        const half8 b0c0 = *(const half8*)(&H0[pu][lane * 8]);
        const half8 b0c1 = *(const half8*)(&H0[pu][512 + lane * 8]);
        const half8 b1c0 = *(const half8*)(&H1[pn][lane * 8]);
        const half8 b1c1 = *(const half8*)(&H1[pn][512 + lane * 8]);
        const float xr   = xs[u * XST + col];

        // layer-0: gates0^u (x enters as rank-1 FMA into the C operand)
        f32x4 t;
        #pragma unroll
        for (int g = 0; g < 4; ++g) t[g] = __builtin_fmaf(wx0[g], xr, bias0[g]);
        f32x4 acc0 = MFMA(A0c0, b0c0, t);
        acc0 = MFMA(A0c1, b0c1, acc0);

        // layer-1: gates1 (bias fed directly as C operand, no movs)
        f32x4 acc1 = MFMA(Aic0, b0c0, bias1);   // Wi1 . h0^u
        acc1 = MFMA(Aic1, b0c1, acc1);
        acc1 = MFMA(Ahc0, b1c0, acc1);          // Wh1 . h1^{u-1}
        acc1 = MFMA(Ahc1, b1c1, acc1);

        const float h0n = cell_update(acc0, ct0);
        H0[pn][wi] = (_Float16)h0n;             // h0^{u+1}
        const float h1n = cell_update(acc1, ct1);
        H1[pu][wi] = (_Float16)h1n;             // h1^u
        __syncthreads();
    }

    // ---- epilogue u=TT: layer-1 only -> h1^TT into hfin ----
    {
        const half8 b0c0 = *(const half8*)(&H0[0][lane * 8]);        // h0^TT
        const half8 b0c1 = *(const half8*)(&H0[0][512 + lane * 8]);
        const half8 b1c0 = *(const half8*)(&H1[1][lane * 8]);        // h1^{TT-1}
        const half8 b1c1 = *(const half8*)(&H1[1][512 + lane * 8]);
        f32x4 acc1 = MFMA(Aic0, b0c0, bias1);
        acc1 = MFMA(Aic1, b0c1, acc1);
        acc1 = MFMA(Ahc0, b1c0, acc1);
        acc1 = MFMA(Ahc1, b1c1, acc1);
        const float h1n = cell_update(acc1, ct1);
        hfin[cellD * NB + col] = h1n;           // cellD 50/51 -> unused slots
        __syncthreads();
    }

    // ---------- FC epilogue: out[b] = fc_b + fc_w . h1^(TT)[b,:] ----------
    if (tid < NB) {
        float s = fc_b[0];
        for (int k = 0; k < HID; ++k)
            s += fc_w[k] * hfin[k * NB + tid];
        out[b0 + tid] = s;
    }
}

extern "C" void kernel_launch(void* const* d_in, const int* in_sizes, int n_in,
                              void* d_out, int out_size, void* d_ws, size_t ws_size,
                              hipStream_t stream) {
    (void)in_sizes; (void)n_in; (void)d_ws; (void)ws_size; (void)out_size;
    const float* x     = (const float*)d_in[0];
    const float* W_ih0 = (const float*)d_in[1];
    const float* W_hh0 = (const float*)d_in[2];
    const float* b_ih0 = (const float*)d_in[3];
    const float* b_hh0 = (const float*)d_in[4];
    const float* W_ih1 = (const float*)d_in[5];
    const float* W_hh1 = (const float*)d_in[6];
    const float* b_ih1 = (const float*)d_in[7];
    const float* b_hh1 = (const float*)d_in[8];
    const float* fc_w  = (const float*)d_in[9];
    const float* fc_b  = (const float*)d_in[10];

    dim3 grid(4096 / NB);   // 256 blocks, 1 per CU
    dim3 block(832);        // 13 waves
    lstm2_mfma_kernel<<<grid, block, 0, stream>>>(
        x, W_ih0, W_hh0, b_ih0, b_hh0,
        W_ih1, W_hh1, b_ih1, b_hh1,
        fc_w, fc_b, (float*)d_out);
}